// Round 14
// baseline (100.351 us; speedup 1.0000x reference)
//
#include <hip/hip_runtime.h>

typedef __attribute__((ext_vector_type(8))) short bf16x8;
typedef __attribute__((ext_vector_type(4))) float f32x4;

#define WT2_BYTES (8ull * 8 * 9 * 8192)           // 4,718,592
#define SINK_OFF  (8u << 20)                      // probe sink at +8 MiB in d_ws

static __device__ __forceinline__ ushort f2bf(float f) {
    union { float f; unsigned u; } v; v.f = f;
    unsigned r = v.u + 0x7FFF + ((v.u >> 16) & 1);   // RNE
    return (ushort)(r >> 16);
}
static __device__ __forceinline__ unsigned cvtpk(float a, float b) {
    unsigned r;
    asm("v_cvt_pk_bf16_f32 %0, %1, %2" : "=v"(r) : "v"(a), "v"(b));
    return r;   // lo = bf16(a), hi = bf16(b)
}

// w: (8 dk, 64 o, 64 i, 8 c, 9 f) fp32 -> wt2 swizzled bf16 image (see r4)
__global__ __launch_bounds__(256) void wprep3_kernel(const float* __restrict__ w,
                                                     ushort* __restrict__ wt) {
    __shared__ float raw[4608];
    __shared__ ushort row[72 * 64];
    int bid = blockIdx.x;
    int dk = bid >> 6, o = bid & 63;
    const float* src = w + (size_t)bid * 4608;
    int t = threadIdx.x;
    #pragma unroll
    for (int j = 0; j < 18; ++j) raw[t + 256 * j] = src[t + 256 * j];
    __syncthreads();
    int osw = o & 7;
    #pragma unroll
    for (int p = 0; p < 18; ++p) {
        int idx = t + 256 * p;
        int cf = idx >> 6, i = idx & 63;
        int c = cf / 9, f = cf - c * 9;
        row[cf * 64 + ((i >> 3) ^ osw) * 8 + (i & 7)] = f2bf(raw[i * 72 + c * 9 + f]);
    }
    __syncthreads();
    char* wb = (char*)wt + (size_t)dk * 8 * 9 * 8192 + o * 128;
    #pragma unroll
    for (int q = 0; q < 3; ++q) {
        int idx = q * 256 + t;
        if (idx < 576) {
            int cf = idx >> 3, cc = idx & 7;
            *(uint4*)(wb + (size_t)cf * 8192 + cc * 16) = *(const uint4*)&row[cf * 64 + cc * 8];
        }
    }
}

// MODE 0: full conv12 (writes d_out).  Probes (write d_ws sink only):
// MODE 1: X-stage only (loads+cvt+ds_write, LDS kept live via readback)
// MODE 2: taps only (loadW + ds_read + MFMA on garbage LDS, acc reduced)
// MODE 3: taps with CONSTANT A-frags (no ds_read) -> MFMA+W-load cost
template <int MODE>
__global__ __launch_bounds__(512, 4) void conv12t_kernel(
    const float* __restrict__ x, const ushort* __restrict__ wt,
    const float* __restrict__ bias, float* __restrict__ out,
    float* __restrict__ sink)
{
    __shared__ __align__(16) ushort XL[264 * 64];   // 33792 B, [r][i] swizzled

    int bid = blockIdx.x;
    int b = bid / 136, rem = bid - b * 136;
    int dk = rem / 17, tile = rem - dk * 17;
    int c, lt;
    if (tile < 14) { c = tile >> 1; lt = tile & 1; } else { c = 7; lt = tile - 14; }
    int Sc = 505 * c, lb = lt << 8;
    int V = ((c == 7) ? 561 : 505) - lb; if (V > 256) V = 256;
    int bdk = b * 8 + dk;
    int R0 = Sc + lb;

    int t = threadIdx.x, lane = t & 63, wv = t >> 6;
    int ln16 = lane & 15, g = lane >> 4;
    int wr = wv >> 1, wc = wv & 1;
    int Lw = wr << 6, Ow = wc << 5;
    int gid = bid * 512 + t;

    // ---- X stage (MODE 0/1 only) ----
    if (MODE <= 1) {
        int lq = t & 63, ig = t >> 6;
        const float* xb = x + (size_t)bdk * 64 * 4096;
        float4 v[8];
        bool edge = (R0 < 4) || (R0 > 3836);
        if (!edge) {
            const float* xp = xb + (size_t)ig * 8 * 4096 + (R0 - 4 + lq * 4);
            #pragma unroll
            for (int j = 0; j < 8; ++j)
                v[j] = *(const float4*)(xp + (size_t)j * 4096);
        } else {
            #pragma unroll
            for (int j = 0; j < 8; ++j) {
                float* pv = (float*)&v[j];
                #pragma unroll
                for (int k = 0; k < 4; ++k) {
                    int xr = R0 - 4 + lq * 4 + k;
                    bool ok = (xr >= 0) && (xr < 4096);
                    int xc = ok ? xr : 0;
                    pv[k] = ok ? xb[(size_t)(ig * 8 + j) * 4096 + xc] : 0.0f;
                }
            }
        }
        float hv[8]; int rh = 0, igh = 0;
        if (t < 64) {
            rh = 256 + (t >> 3); igh = t & 7;
            int xr = R0 - 4 + rh;
            bool okh = xr < 4096;
            int xc = okh ? xr : 0;
            const float* xh = xb + (size_t)igh * 8 * 4096 + xc;
            #pragma unroll
            for (int j = 0; j < 8; ++j) hv[j] = okh ? xh[(size_t)j * 4096] : 0.0f;
        }
        #pragma unroll
        for (int k = 0; k < 4; ++k) {
            int r = lq * 4 + k;
            uint4 A;
            A.x = cvtpk(((const float*)&v[0])[k], ((const float*)&v[1])[k]);
            A.y = cvtpk(((const float*)&v[2])[k], ((const float*)&v[3])[k]);
            A.z = cvtpk(((const float*)&v[4])[k], ((const float*)&v[5])[k]);
            A.w = cvtpk(((const float*)&v[6])[k], ((const float*)&v[7])[k]);
            *(uint4*)((char*)XL + r * 128 + ((ig ^ (r & 7)) * 16)) = A;
        }
        if (t < 64) {
            uint4 A;
            A.x = cvtpk(hv[0], hv[1]); A.y = cvtpk(hv[2], hv[3]);
            A.z = cvtpk(hv[4], hv[5]); A.w = cvtpk(hv[6], hv[7]);
            *(uint4*)((char*)XL + rh * 128 + ((igh ^ (rh & 7)) * 16)) = A;
        }
    }

    // ---- W addressing + fragment regs ----
    const char* wsl = (const char*)wt + (size_t)(dk * 8 + c) * 9 * 8192;
    int wo[2][2];
    #pragma unroll
    for (int s = 0; s < 2; ++s)
        #pragma unroll
        for (int nf = 0; nf < 2; ++nf)
            wo[s][nf] = (Ow + nf * 16 + ln16) * 128 + (((s * 4 + g) ^ (ln16 & 7)) * 16);

    bf16x8 w0[2][2], w1[2][2];
    auto loadW = [&](bf16x8 (&d)[2][2], int f) {
        const char* bp = wsl + (size_t)f * 8192;
        #pragma unroll
        for (int s = 0; s < 2; ++s)
            #pragma unroll
            for (int nf = 0; nf < 2; ++nf)
                d[s][nf] = *(const bf16x8*)(bp + wo[s][nf]);
    };
    if (MODE != 1) { loadW(w0, 0); loadW(w1, 1); }

    asm volatile("s_waitcnt lgkmcnt(0)" ::: "memory");
    __syncthreads();

    if (MODE == 1) {   // stage probe: keep XL live via readback, then exit
        uint4 q = *(const uint4*)((const char*)XL + ((t * 66) & 33776));
        sink[gid] = __uint_as_float(q.x ^ q.y ^ q.z ^ q.w);
        return;
    }

    // constant A-frag for MODE 3 (no ds_read in taps)
    bf16x8 avc;
    if (MODE == 3) {
        unsigned pk = cvtpk(0.5f, -0.5f);
        union { unsigned u[4]; bf16x8 v8; } uu;
        uu.u[0] = pk; uu.u[1] = pk ^ 1; uu.u[2] = pk ^ 2; uu.u[3] = pk ^ 3;
        avc = uu.v8;
    }

    f32x4 acc[4][2];
    #pragma unroll
    for (int a0 = 0; a0 < 4; ++a0)
        #pragma unroll
        for (int a1 = 0; a1 < 2; ++a1) acc[a0][a1] = (f32x4){0.f, 0.f, 0.f, 0.f};

    auto tap = [&](int f, bf16x8 (&wf)[2][2]) {
        int rbase = Lw + ln16 + f;
        int swz = rbase & 7;
        #pragma unroll
        for (int s = 0; s < 2; ++s) {
            int cof = ((s * 4 + g) ^ swz) * 16;
            bf16x8 av[4];
            #pragma unroll
            for (int mf = 0; mf < 4; ++mf)
                av[mf] = (MODE == 3) ? avc
                    : *(const bf16x8*)((const char*)XL + (rbase + mf * 16) * 128 + cof);
            __builtin_amdgcn_s_setprio(1);
            #pragma unroll
            for (int mf = 0; mf < 4; ++mf)
                #pragma unroll
                for (int nf = 0; nf < 2; ++nf)
                    acc[mf][nf] = __builtin_amdgcn_mfma_f32_16x16x32_bf16(av[mf], wf[s][nf], acc[mf][nf], 0, 0, 0);
            __builtin_amdgcn_s_setprio(0);
        }
    };

    tap(0, w0); loadW(w0, 2);
    tap(1, w1); loadW(w1, 3);
    tap(2, w0); loadW(w0, 4);
    tap(3, w1); loadW(w1, 5);
    tap(4, w0); loadW(w0, 6);
    tap(5, w1); loadW(w1, 7);
    tap(6, w0); loadW(w0, 8);
    tap(7, w1);
    tap(8, w0);

    if (MODE == 0) {
        float* ob = out + ((size_t)(bdk * 64)) * 4096 + Sc + lb;
        #pragma unroll
        for (int nf = 0; nf < 2; ++nf) {
            int o = Ow + nf * 16 + ln16;
            float bvs = bias[(dk * 64 + o) * 8 + c];
            #pragma unroll
            for (int mf = 0; mf < 4; ++mf) {
                int l = Lw + mf * 16 + g * 4;
                f32x4 vv = acc[mf][nf];
                vv[0] += bvs; vv[1] += bvs; vv[2] += bvs; vv[3] += bvs;
                if (l + 4 <= V) {
                    *(f32x4*)(ob + (size_t)o * 4096 + l) = vv;
                } else if (l < V) {
                    #pragma unroll
                    for (int r = 0; r < 4; ++r)
                        if (l + r < V) ob[(size_t)o * 4096 + l + r] = vv[r];
                }
            }
        }
    } else {           // probe epilogue: reduce acc to 1 float/thread
        float s = 0.f;
        #pragma unroll
        for (int mf = 0; mf < 4; ++mf)
            #pragma unroll
            for (int nf = 0; nf < 2; ++nf)
                #pragma unroll
                for (int r = 0; r < 4; ++r) s += acc[mf][nf][r];
        sink[gid] = s;
    }
}

extern "C" void kernel_launch(void* const* d_in, const int* in_sizes, int n_in,
                              void* d_out, int out_size, void* d_ws, size_t ws_size,
                              hipStream_t stream) {
    const float* x    = (const float*)d_in[0];
    const float* wgt  = (const float*)d_in[1];
    const float* bias = (const float*)d_in[2];
    float* out        = (float*)d_out;
    ushort* wt2       = (ushort*)d_ws;
    float* sink       = (float*)((char*)d_ws + SINK_OFF);

    hipLaunchKernelGGL(wprep3_kernel, dim3(512), dim3(256), 0, stream, wgt, wt2);
    // real kernel (validated output)
    hipLaunchKernelGGL((conv12t_kernel<0>), dim3(1088), dim3(512), 0, stream, x, wt2, bias, out, sink);
    // ablation probes (d_ws only) — per-dispatch timings decompose the 50 us
    hipLaunchKernelGGL((conv12t_kernel<1>), dim3(1088), dim3(512), 0, stream, x, wt2, bias, out, sink);
    hipLaunchKernelGGL((conv12t_kernel<2>), dim3(1088), dim3(512), 0, stream, x, wt2, bias, out, sink);
    hipLaunchKernelGGL((conv12t_kernel<3>), dim3(1088), dim3(512), 0, stream, x, wt2, bias, out, sink);
}

// Round 15
// 75.428 us; speedup vs baseline: 1.3304x; 1.3304x over previous
//
#include <hip/hip_runtime.h>

typedef __attribute__((ext_vector_type(8))) short bf16x8;
typedef __attribute__((ext_vector_type(4))) float f32x4;

#define WT2_BYTES (8ull * 8 * 9 * 8192)           // 4,718,592

static __device__ __forceinline__ ushort f2bf(float f) {
    union { float f; unsigned u; } v; v.f = f;
    unsigned r = v.u + 0x7FFF + ((v.u >> 16) & 1);   // RNE
    return (ushort)(r >> 16);
}
static __device__ __forceinline__ unsigned cvtpk(float a, float b) {
    unsigned r;
    asm("v_cvt_pk_bf16_f32 %0, %1, %2" : "=v"(r) : "v"(a), "v"(b));
    return r;   // lo = bf16(a), hi = bf16(b)
}

// w: (8 dk, 64 o, 64 i, 8 c, 9 f) fp32
// -> wt2: (8 dk, 8 c, 9 f) slices of 8192 B; element (o,i) at byte
//    o*128 + ((i>>3) ^ (o&7))*16 + (i&7)*2   (XOR-swizzle baked in)
__global__ __launch_bounds__(256) void wprep3_kernel(const float* __restrict__ w,
                                                     ushort* __restrict__ wt) {
    __shared__ float raw[4608];
    __shared__ ushort row[72 * 64];
    int bid = blockIdx.x;
    int dk = bid >> 6, o = bid & 63;
    const float* src = w + (size_t)bid * 4608;
    int t = threadIdx.x;
    #pragma unroll
    for (int j = 0; j < 18; ++j) raw[t + 256 * j] = src[t + 256 * j];
    __syncthreads();
    int osw = o & 7;
    #pragma unroll
    for (int p = 0; p < 18; ++p) {
        int idx = t + 256 * p;
        int cf = idx >> 6, i = idx & 63;
        int c = cf / 9, f = cf - c * 9;
        row[cf * 64 + ((i >> 3) ^ osw) * 8 + (i & 7)] = f2bf(raw[i * 72 + c * 9 + f]);
    }
    __syncthreads();
    char* wb = (char*)wt + (size_t)dk * 8 * 9 * 8192 + o * 128;
    #pragma unroll
    for (int q = 0; q < 3; ++q) {
        int idx = q * 256 + t;
        if (idx < 576) {
            int cf = idx >> 3, cc = idx & 7;
            *(uint4*)(wb + (size_t)cf * 8192 + cc * 16) = *(const uint4*)&row[cf * 64 + cc * 8];
        }
    }
}

// conv13: persistent-2 (grid 544, tiles 2*bid and 2*bid+1). conv12 tile body
// (256l x 64o, 8 waves of 64l x 32o, W in regs, 1 barrier/tile) + NEXT-TILE
// X prefetch overlapped with current taps: loads issued at tap0/tap3 into
// regs, cvt+ds_write after tap8 into XL[p^1]. Phases (fetch/compute/store)
// mix inside the block instead of serializing GPU-wide.
__global__ __launch_bounds__(512, 4) void conv13_kernel(
    const float* __restrict__ x, const ushort* __restrict__ wt,
    const float* __restrict__ bias, float* __restrict__ out)
{
    __shared__ __align__(16) ushort XL[2][264 * 64];   // 2 x 33792 B

    int t = threadIdx.x, lane = t & 63, wv = t >> 6;
    int ln16 = lane & 15, g = lane >> 4;
    int wr = wv >> 1, wc = wv & 1;
    int Lw = wr << 6, Ow = wc << 5;                 // 64l x 32o per wave
    int lq = t & 63, ig = t >> 6;                   // stage mapping

    auto dec = [&](int tid, int& bdk, int& dk, int& c, int& V, int& R0) {
        int b = tid / 136, rem = tid - b * 136;
        dk = rem / 17; int tile = rem - dk * 17;
        int lt;
        if (tile < 14) { c = tile >> 1; lt = tile & 1; } else { c = 7; lt = tile - 14; }
        int lb = lt << 8;
        V = ((c == 7) ? 561 : 505) - lb; if (V > 256) V = 256;
        R0 = 505 * c + lb;
        bdk = b * 8 + dk;
    };

    // W fragment per-lane byte offsets (swizzled image)
    int wo[2][2];
    #pragma unroll
    for (int s = 0; s < 2; ++s)
        #pragma unroll
        for (int nf = 0; nf < 2; ++nf)
            wo[s][nf] = (Ow + nf * 16 + ln16) * 128 + (((s * 4 + g) ^ (ln16 & 7)) * 16);

    const char* wsl = nullptr;
    bf16x8 w0[2][2], w1[2][2];
    auto loadW = [&](bf16x8 (&d)[2][2], int f) {
        const char* bp = wsl + (size_t)f * 8192;
        #pragma unroll
        for (int s = 0; s < 2; ++s)
            #pragma unroll
            for (int nf = 0; nf < 2; ++nf)
                d[s][nf] = *(const bf16x8*)(bp + wo[s][nf]);
    };

    // ---- staging helpers (half h covers i-rows ig*8 + h*4 .. +3) ----
    float4 vA[4], vB[4]; float hv[8];
    auto issueHalf = [&](int bdkX, int R0X, int h, float4 (&v)[4]) {
        const float* xb = x + (size_t)bdkX * 64 * 4096;
        bool edge = (R0X < 4) || (R0X > 3836);
        if (!edge) {
            const float* xp = xb + (size_t)(ig * 8 + h * 4) * 4096 + (R0X - 4 + lq * 4);
            #pragma unroll
            for (int j = 0; j < 4; ++j)
                v[j] = *(const float4*)(xp + (size_t)j * 4096);
        } else {
            #pragma unroll
            for (int j = 0; j < 4; ++j) {
                float* pv = (float*)&v[j];
                #pragma unroll
                for (int k = 0; k < 4; ++k) {
                    int xr = R0X - 4 + lq * 4 + k;
                    bool ok = (xr >= 0) && (xr < 4096);
                    int xc = ok ? xr : 0;
                    pv[k] = ok ? xb[(size_t)(ig * 8 + h * 4 + j) * 4096 + xc] : 0.0f;
                }
            }
        }
    };
    auto issueHalo = [&](int bdkX, int R0X) {
        if (t < 64) {
            int rh = 256 + (t >> 3), igh = t & 7;
            int xr = R0X - 4 + rh;                  // >= 252 always
            bool okh = xr < 4096;
            int xc = okh ? xr : 0;
            const float* xh = x + (size_t)bdkX * 64 * 4096 + (size_t)igh * 8 * 4096 + xc;
            #pragma unroll
            for (int j = 0; j < 8; ++j) hv[j] = okh ? xh[(size_t)j * 4096] : 0.0f;
        }
    };
    auto writeTile = [&](ushort* dst) {
        #pragma unroll
        for (int k = 0; k < 4; ++k) {
            int r = lq * 4 + k;
            uint4 A;
            A.x = cvtpk(((const float*)&vA[0])[k], ((const float*)&vA[1])[k]);
            A.y = cvtpk(((const float*)&vA[2])[k], ((const float*)&vA[3])[k]);
            A.z = cvtpk(((const float*)&vB[0])[k], ((const float*)&vB[1])[k]);
            A.w = cvtpk(((const float*)&vB[2])[k], ((const float*)&vB[3])[k]);
            *(uint4*)((char*)dst + r * 128 + ((ig ^ (r & 7)) * 16)) = A;
        }
        if (t < 64) {
            int rh = 256 + (t >> 3), igh = t & 7;
            uint4 A;
            A.x = cvtpk(hv[0], hv[1]); A.y = cvtpk(hv[2], hv[3]);
            A.z = cvtpk(hv[4], hv[5]); A.w = cvtpk(hv[6], hv[7]);
            *(uint4*)((char*)dst + rh * 128 + ((igh ^ (rh & 7)) * 16)) = A;
        }
    };

    f32x4 acc[4][2];
    auto tap = [&](const char* xbuf, int f, bf16x8 (&wf)[2][2]) {
        int rbase = Lw + ln16 + f;
        int swz = rbase & 7;
        #pragma unroll
        for (int s = 0; s < 2; ++s) {
            int cof = ((s * 4 + g) ^ swz) * 16;
            bf16x8 av[4];
            #pragma unroll
            for (int mf = 0; mf < 4; ++mf)
                av[mf] = *(const bf16x8*)(xbuf + (rbase + mf * 16) * 128 + cof);
            __builtin_amdgcn_s_setprio(1);
            #pragma unroll
            for (int mf = 0; mf < 4; ++mf)
                #pragma unroll
                for (int nf = 0; nf < 2; ++nf)
                    acc[mf][nf] = __builtin_amdgcn_mfma_f32_16x16x32_bf16(av[mf], wf[s][nf], acc[mf][nf], 0, 0, 0);
            __builtin_amdgcn_s_setprio(0);
        }
    };
    auto epilogue = [&](int bdk, int dk, int c, int V, int R0) {
        float* ob = out + ((size_t)(bdk * 64)) * 4096 + R0;
        #pragma unroll
        for (int nf = 0; nf < 2; ++nf) {
            int o = Ow + nf * 16 + ln16;
            float bvs = bias[(dk * 64 + o) * 8 + c];
            #pragma unroll
            for (int mf = 0; mf < 4; ++mf) {
                int l = Lw + mf * 16 + g * 4;
                f32x4 vv = acc[mf][nf];
                vv[0] += bvs; vv[1] += bvs; vv[2] += bvs; vv[3] += bvs;
                if (l + 4 <= V) {
                    *(f32x4*)(ob + (size_t)o * 4096 + l) = vv;
                } else if (l < V) {
                    #pragma unroll
                    for (int r = 0; r < 4; ++r)
                        if (l + r < V) ob[(size_t)o * 4096 + l + r] = vv[r];
                }
            }
        }
    };

    int t0 = 2 * blockIdx.x, t1 = t0 + 1;
    int bdk0, dk0, c0, V0, R00, bdk1, dk1, c1, V1, R01;
    dec(t0, bdk0, dk0, c0, V0, R00);
    dec(t1, bdk1, dk1, c1, V1, R01);

    // ---- prologue: stage tile 0 ----
    issueHalf(bdk0, R00, 0, vA);
    issueHalf(bdk0, R00, 1, vB);
    issueHalo(bdk0, R00);
    writeTile(XL[0]);
    __syncthreads();

    // ---- tile 0 body (tile-1 stage overlapped) ----
    wsl = (const char*)wt + (size_t)(dk0 * 8 + c0) * 9 * 8192;
    loadW(w0, 0); loadW(w1, 1);
    #pragma unroll
    for (int a0 = 0; a0 < 4; ++a0)
        #pragma unroll
        for (int a1 = 0; a1 < 2; ++a1) acc[a0][a1] = (f32x4){0.f, 0.f, 0.f, 0.f};

    issueHalf(bdk1, R01, 0, vA);                   // prefetch issue (early)
    __builtin_amdgcn_sched_barrier(0);
    const char* xc = (const char*)XL[0];
    tap(xc, 0, w0); loadW(w0, 2);
    tap(xc, 1, w1); loadW(w1, 3);
    tap(xc, 2, w0); loadW(w0, 4);
    tap(xc, 3, w1); loadW(w1, 5);
    issueHalf(bdk1, R01, 1, vB);                   // prefetch issue (late half)
    issueHalo(bdk1, R01);
    __builtin_amdgcn_sched_barrier(0);
    tap(xc, 4, w0); loadW(w0, 6);
    tap(xc, 5, w1); loadW(w1, 7);
    tap(xc, 6, w0); loadW(w0, 8);
    tap(xc, 7, w1);
    tap(xc, 8, w0);
    epilogue(bdk0, dk0, c0, V0, R00);              // stores overlap next stage
    writeTile(XL[1]);                              // cvt+ds_write (waits loads)
    __syncthreads();

    // ---- tile 1 body ----
    wsl = (const char*)wt + (size_t)(dk1 * 8 + c1) * 9 * 8192;
    loadW(w0, 0); loadW(w1, 1);
    #pragma unroll
    for (int a0 = 0; a0 < 4; ++a0)
        #pragma unroll
        for (int a1 = 0; a1 < 2; ++a1) acc[a0][a1] = (f32x4){0.f, 0.f, 0.f, 0.f};
    xc = (const char*)XL[1];
    tap(xc, 0, w0); loadW(w0, 2);
    tap(xc, 1, w1); loadW(w1, 3);
    tap(xc, 2, w0); loadW(w0, 4);
    tap(xc, 3, w1); loadW(w1, 5);
    tap(xc, 4, w0); loadW(w0, 6);
    tap(xc, 5, w1); loadW(w1, 7);
    tap(xc, 6, w0); loadW(w0, 8);
    tap(xc, 7, w1);
    tap(xc, 8, w0);
    epilogue(bdk1, dk1, c1, V1, R01);
}

extern "C" void kernel_launch(void* const* d_in, const int* in_sizes, int n_in,
                              void* d_out, int out_size, void* d_ws, size_t ws_size,
                              hipStream_t stream) {
    const float* x    = (const float*)d_in[0];
    const float* wgt  = (const float*)d_in[1];
    const float* bias = (const float*)d_in[2];
    float* out        = (float*)d_out;
    ushort* wt2       = (ushort*)d_ws;            // 4,718,592 B

    hipLaunchKernelGGL(wprep3_kernel, dim3(512), dim3(256), 0, stream, wgt, wt2);
    hipLaunchKernelGGL(conv13_kernel, dim3(544), dim3(512), 0, stream, x, wt2, bias, out);
}